// Round 2
// baseline (436.813 us; speedup 1.0000x reference)
//
#include <hip/hip_runtime.h>

// out[b,n,k] = |x[b,n,k]| * (1 - w[b,k]*C/(C-1)) + w[b,k]/(C-1) * S[b,n]
// with S[b,n] = sum_c |x[b,n,c]|.  B=64, N=1024, C=1000.
//
// One WAVE per row (no __syncthreads, no LDS): lane L handles columns
// c = j*256 + L*4 + {0..3}, j=0..3 (covers 1024 >= 1000, j=3 tail masked).
// Waves are persistent per b: w-row coefficients live in registers across
// the 8 rows each wave processes.

constexpr int B = 64;
constexpr int N = 1024;
constexpr int C = 1000;
constexpr int BLOCKS_PER_B   = 32;                        // grid = 64*32 = 2048
constexpr int WAVES_PER_BLOCK = 4;                        // 256 threads
constexpr int WAVES_PER_B    = BLOCKS_PER_B * WAVES_PER_BLOCK; // 128 -> 8 rows/wave

__global__ __launch_bounds__(256) void wf_kernel(
    const float* __restrict__ x,   // [B,N,C]
    const float* __restrict__ w,   // [B,C]
    float* __restrict__ out)       // [B,N,C]
{
    const int b       = blockIdx.x >> 5;         // / BLOCKS_PER_B
    const int blkInB  = blockIdx.x & 31;
    const int wave    = threadIdx.x >> 6;
    const int lane    = threadIdx.x & 63;
    const int waveInB = blkInB * WAVES_PER_BLOCK + wave;   // 0..127

    constexpr float inv = 1.0f / (float)(C - 1);
    const bool v3 = (768 + lane * 4) < C;        // j=3 tail guard (j<3 always valid)

    // Per-lane column coefficients, loaded once per wave.
    float A[16], Bc[16];
    #pragma unroll
    for (int j = 0; j < 4; ++j) {
        const int c0 = j * 256 + lane * 4;
        float4 wv = make_float4(0.f, 0.f, 0.f, 0.f);
        if (j < 3 || v3)
            wv = *reinterpret_cast<const float4*>(w + (long long)b * C + c0);
        A[j*4+0] = 1.0f - wv.x - wv.x * inv;  Bc[j*4+0] = wv.x * inv;
        A[j*4+1] = 1.0f - wv.y - wv.y * inv;  Bc[j*4+1] = wv.y * inv;
        A[j*4+2] = 1.0f - wv.z - wv.z * inv;  Bc[j*4+2] = wv.z * inv;
        A[j*4+3] = 1.0f - wv.w - wv.w * inv;  Bc[j*4+3] = wv.w * inv;
    }

    for (int n = waveInB; n < N; n += WAVES_PER_B) {
        const long long base = (long long)(b * N + n) * C;

        float a[16];
        #pragma unroll
        for (int j = 0; j < 4; ++j) {
            const int c0 = j * 256 + lane * 4;
            if (j < 3 || v3) {
                float4 xv = *reinterpret_cast<const float4*>(x + base + c0);
                a[j*4+0] = fabsf(xv.x);
                a[j*4+1] = fabsf(xv.y);
                a[j*4+2] = fabsf(xv.z);
                a[j*4+3] = fabsf(xv.w);
            } else {
                a[12] = a[13] = a[14] = a[15] = 0.f;
            }
        }

        // pairwise per-lane sum, then 64-lane butterfly (all lanes get S)
        float s01 = (a[0] + a[1]) + (a[2] + a[3]);
        float s23 = (a[4] + a[5]) + (a[6] + a[7]);
        float s45 = (a[8] + a[9]) + (a[10] + a[11]);
        float s67 = (a[12] + a[13]) + (a[14] + a[15]);
        float S = (s01 + s23) + (s45 + s67);
        #pragma unroll
        for (int off = 1; off < 64; off <<= 1)
            S += __shfl_xor(S, off, 64);

        #pragma unroll
        for (int j = 0; j < 4; ++j) {
            const int c0 = j * 256 + lane * 4;
            if (j < 3 || v3) {
                float4 o;
                o.x = a[j*4+0] * A[j*4+0] + Bc[j*4+0] * S;
                o.y = a[j*4+1] * A[j*4+1] + Bc[j*4+1] * S;
                o.z = a[j*4+2] * A[j*4+2] + Bc[j*4+2] * S;
                o.w = a[j*4+3] * A[j*4+3] + Bc[j*4+3] * S;
                *reinterpret_cast<float4*>(out + base + c0) = o;
            }
        }
    }
}

extern "C" void kernel_launch(void* const* d_in, const int* in_sizes, int n_in,
                              void* d_out, int out_size, void* d_ws, size_t ws_size,
                              hipStream_t stream) {
    const float* x = (const float*)d_in[0];   // residual [B,N,C]
    const float* w = (const float*)d_in[1];   // weight   [B,C]
    float* out = (float*)d_out;               // [B,N,C]
    (void)in_sizes; (void)n_in; (void)d_ws; (void)ws_size; (void)out_size;

    wf_kernel<<<B * BLOCKS_PER_B, WAVES_PER_BLOCK * 64, 0, stream>>>(x, w, out);
}